// Round 6
// baseline (228.637 us; speedup 1.0000x reference)
//
#include <hip/hip_runtime.h>

#define D     512
#define HW    (D * D)
#define BLOCK 256
#define RPB   4            // rows per block; wave w owns cols [128w, 128w+128)

// General path: full reference bilinear with per-lane gathers (ind = y + D*x).
__device__ __forceinline__ void samp_gather(const float* __restrict__ im,
    float rx, float ry, float m, float r3[3], float* oob)
{
    float cxq = fminf(fmaxf(rx, 0.001f), 510.999f);
    float cyq = fminf(fmaxf(ry, 0.001f), 510.999f);
    float dx = rx - cxq, dy = ry - cyq;
    *oob += dx * dx + dy * dy;
    float xff = floorf(cxq), xcf = ceilf(cxq);
    float yff = floorf(cyq), ycf = ceilf(cyq);
    float wxf = 1.0f - (cxq - xff), wxc = 1.0f - (xcf - cxq);
    float wyf = 1.0f - (cyq - yff), wyc = 1.0f - (ycf - cyq);
    float w00 = wxf * wyf, w10 = wxc * wyf, w01 = wxf * wyc, w11 = wxc * wyc;
    int xf = (int)xff, xc = (int)xcf, yf = (int)yff, yc = (int)ycf;
    int i00 = yf + D * xf, i10 = yf + D * xc;
    int i01 = yc + D * xf, i11 = yc + D * xc;
#pragma unroll
    for (int c = 0; c < 3; ++c) {
        const float* __restrict__ ch = im + (size_t)c * HW;
        r3[c] += m * (w00 * ch[i00] + w10 * ch[i10] + w01 * ch[i01] + w11 * ch[i11]);
    }
}

__global__ void __launch_bounds__(BLOCK) vm_kernel(
    const float* __restrict__ im1, const float* __restrict__ im2,
    const float* __restrict__ C,   const float* __restrict__ M1,
    const float* __restrict__ M2,  float* __restrict__ out,
    double* __restrict__ partials)
{
    int b  = blockIdx.x;
    int n  = b >> 7;                       // 128 row-groups per image
    int i0 = (b & 127) * RPB;              // first of 4 rows
    int w  = threadIdx.x >> 6;             // wave: col slice [128w, 128w+128)
    int l  = threadIdx.x & 63;
    int c0 = w * 128 + l * 2;              // this thread's 2 columns

    const float* base1 = im1 + (size_t)n * 3 * HW;
    const float* base2 = im2 + (size_t)n * 3 * HW;

    // Fully-clipped-high sample value is block-uniform (clipped coord is the
    // constant 510.999f -> constant weights). Exact f32 replication.
    const float WF = 1.0f - (510.999f - 510.0f);
    const float WC = 1.0f - (511.0f - 510.999f);
    float S1[3], S2[3];
#pragma unroll
    for (int c = 0; c < 3; ++c) {
        const float* c1 = base1 + (size_t)c * HW;
        const float* c2 = base2 + (size_t)c * HW;
        S1[c] = (WF * WF) * c1[510 + D * 510] + (WC * WF) * c1[510 + D * 511]
              + (WF * WC) * c1[511 + D * 510] + (WC * WC) * c1[511 + D * 511];
        S2[c] = (WF * WF) * c2[510 + D * 510] + (WC * WF) * c2[510 + D * 511]
              + (WF * WC) * c2[511 + D * 510] + (WC * WC) * c2[511 + D * 511];
    }

    size_t cb = (size_t)n * 2 * HW, mb = (size_t)n * HW, ob = (size_t)n * 3 * HW;

    // ---- phase 1: issue all 16 independent stream loads (max MLP) ----
    float2 cxv[RPB], cyv[RPB], m1v[RPB], m2v[RPB];
    size_t roff[RPB];
#pragma unroll
    for (int r = 0; r < RPB; ++r) {
        roff[r] = (size_t)(i0 + r) * D + c0;
        cxv[r] = *(const float2*)(C  + cb + roff[r]);
        cyv[r] = *(const float2*)(C  + cb + HW + roff[r]);
        m1v[r] = *(const float2*)(M1 + mb + roff[r]);
        m2v[r] = *(const float2*)(M2 + mb + roff[r]);
    }

    // ---- phase 2: compute 8 pixels ----
    float o0[RPB][2], o1[RPB][2], o2[RPB][2];
    float oob = 0.0f;
#pragma unroll
    for (int r = 0; r < RPB; ++r) {
        float fi = (float)(i0 + r);
#pragma unroll
        for (int k = 0; k < 2; ++k) {
            float cx  = k ? cxv[r].y : cxv[r].x;
            float cy  = k ? cyv[r].y : cyv[r].x;
            float m1s = k ? m1v[r].y : m1v[r].x;
            float m2s = k ? m2v[r].y : m2v[r].x;
            float fj  = (float)(c0 + k);

            float tot = m1s + m2s;
            float inv = 1.0f / tot;
            float m1n = m1s * inv, m2n = m2s * inv;

            float rx1 = (fi + cx) * 512.0f, ry1 = (fj + cy) * 512.0f;
            float rx2 = (fi - cx) * 512.0f, ry2 = (fj - cy) * 512.0f;

            // exact: (fi-|cx|)*512 == min(rx1,rx2) in f32
            bool fast = ((fi - fabsf(cx)) * 512.0f >= 510.999f)
                     && ((fj - fabsf(cy)) * 512.0f >= 510.999f);

            float r3[3];
            if (fast) {
                float dx1 = rx1 - 510.999f, dy1 = ry1 - 510.999f;
                float dx2 = rx2 - 510.999f, dy2 = ry2 - 510.999f;
                oob += dx1 * dx1 + dy1 * dy1 + dx2 * dx2 + dy2 * dy2;
                r3[0] = m1n * S1[0] + m2n * S2[0];
                r3[1] = m1n * S1[1] + m2n * S2[1];
                r3[2] = m1n * S1[2] + m2n * S2[2];
            } else {
                r3[0] = r3[1] = r3[2] = 0.0f;
                samp_gather(base1, rx1, ry1, m1n, r3, &oob);
                samp_gather(base2, rx2, ry2, m2n, r3, &oob);
            }
            o0[r][k] = r3[0]; o1[r][k] = r3[1]; o2[r][k] = r3[2];
        }
    }

    // ---- phase 3: stores ----
#pragma unroll
    for (int r = 0; r < RPB; ++r) {
        *(float2*)(out + ob + roff[r])          = make_float2(o0[r][0], o0[r][1]);
        *(float2*)(out + ob + HW + roff[r])     = make_float2(o1[r][0], o1[r][1]);
        *(float2*)(out + ob + 2 * HW + roff[r]) = make_float2(o2[r][0], o2[r][1]);
    }

    // ---- per-WAVE oob reduction: no __syncthreads, waves retire alone ----
    for (int off = 32; off > 0; off >>= 1)
        oob += __shfl_down(oob, off, 64);
    if (l == 0)
        partials[(size_t)b * (BLOCK / 64) + w] = (double)oob;
}

__global__ void __launch_bounds__(BLOCK) reduce_kernel(
    const double* __restrict__ partials, int nparts,
    float* __restrict__ out_last, double scale)
{
    double s = 0.0;
    for (int i = threadIdx.x; i < nparts; i += BLOCK)
        s += partials[i];
    for (int off = 32; off > 0; off >>= 1)
        s += __shfl_down(s, off, 64);

    __shared__ double sm[BLOCK / 64];
    int lane = threadIdx.x & 63;
    int w    = threadIdx.x >> 6;
    if (lane == 0) sm[w] = s;
    __syncthreads();
    if (threadIdx.x == 0)
        *out_last = (float)((sm[0] + sm[1] + sm[2] + sm[3]) * scale);
}

extern "C" void kernel_launch(void* const* d_in, const int* in_sizes, int n_in,
                              void* d_out, int out_size, void* d_ws, size_t ws_size,
                              hipStream_t stream) {
    const float* im1 = (const float*)d_in[0];
    const float* im2 = (const float*)d_in[1];
    const float* C   = (const float*)d_in[2];
    const float* M1  = (const float*)d_in[3];
    const float* M2  = (const float*)d_in[4];
    float* out = (float*)d_out;
    double* ws = (double*)d_ws;

    int N = in_sizes[3] / HW;            // M1 is [N,1,H,W]
    int blocks = N * (D / RPB);          // 2048
    int nparts = blocks * (BLOCK / 64);  // one partial per wave: 8192

    vm_kernel<<<blocks, BLOCK, 0, stream>>>(im1, im2, C, M1, M2, out, ws);

    // loss = sum / (N*2*HW) / D^2 * 1e-4  (a and b share the mean count)
    double scale = 1.0 / ((double)N * 2.0 * (double)HW) / (double)HW * 1e-4;
    reduce_kernel<<<1, BLOCK, 0, stream>>>(ws, nparts, out + (out_size - 1), scale);
}